// Round 2
// baseline (3173.823 us; speedup 1.0000x reference)
//
#include <hip/hip_runtime.h>
#include <hip/hip_bf16.h>
#include <cstdint>
#include <cstddef>

#define TNUM 8192
#define DDIM 2048
#define FDIM 4096
#define NEXP 8

typedef __attribute__((ext_vector_type(4))) float f32x4;
typedef __attribute__((ext_vector_type(8))) short s16x8;
typedef __attribute__((ext_vector_type(8))) __bf16 bf16x8v;

__device__ inline f32x4 mfma16(s16x8 a, s16x8 b, f32x4 c) {
  return __builtin_amdgcn_mfma_f32_16x16x32_bf16(
      __builtin_bit_cast(bf16x8v, a), __builtin_bit_cast(bf16x8v, b), c, 0, 0, 0);
}

// round-to-nearest-even fp32 -> bf16 bits
__device__ inline unsigned short bf16r(float f) {
  union { float f; unsigned u; } x; x.f = f;
  unsigned r = x.u + 0x7fffu + ((x.u >> 16) & 1u);
  return (unsigned short)(r >> 16);
}

// XOR swizzle within 128-byte rows (G4): bijective per row, same fn on write+read
__device__ inline int swz16(int row, int b) {
  return (row << 7) + (b ^ ((row & 7) << 4));
}

// ---------------- router: fp64 logits, top-2 on logits, fp32 softmax values --
__global__ __launch_bounds__(256) void k_router(
    const float* __restrict__ x, const float* __restrict__ gw,
    int* __restrict__ top_idx, float* __restrict__ top_w, int* __restrict__ counts) {
  __shared__ float gwT[NEXP][DDIM];  // 64KB, transposed for conflict-free reads
  const int tid = threadIdx.x;
  for (int i = tid; i < NEXP * DDIM; i += 256) {
    int d = i >> 3, e = i & 7;
    gwT[e][d] = gw[i];
  }
  __syncthreads();
  const int lane = tid & 63;
  const int t = blockIdx.x * 4 + (tid >> 6);
  const float4* xr = (const float4*)(x + (size_t)t * DDIM);
  double acc[NEXP];
#pragma unroll
  for (int e = 0; e < NEXP; e++) acc[e] = 0.0;
  for (int d4 = lane; d4 < DDIM / 4; d4 += 64) {
    float4 xv = xr[d4];
#pragma unroll
    for (int e = 0; e < NEXP; e++) {
      float4 gv = *(const float4*)&gwT[e][d4 * 4];
      acc[e] += (double)xv.x * gv.x + (double)xv.y * gv.y +
                (double)xv.z * gv.z + (double)xv.w * gv.w;
    }
  }
#pragma unroll
  for (int e = 0; e < NEXP; e++) {
    double v = acc[e];
#pragma unroll
    for (int s = 32; s > 0; s >>= 1) v += __shfl_xor(v, s);
    acc[e] = v;
  }
  if (lane == 0) {
    // top-2 by fp64 logits (softcap+softmax are monotonic; ties -> lowest idx)
    int i0 = 0; double b0 = acc[0];
#pragma unroll
    for (int e = 1; e < NEXP; e++) if (acc[e] > b0) { b0 = acc[e]; i0 = e; }
    int i1 = (i0 == 0) ? 1 : 0; double b1 = acc[i1];
#pragma unroll
    for (int e = 0; e < NEXP; e++) {
      if (e == i0 || e == i1) continue;
      if (acc[e] > b1) { b1 = acc[e]; i1 = e; }
    }
    // softmax values in fp32 over softcapped logits
    float lc[NEXP]; float mx = -1e30f;
#pragma unroll
    for (int e = 0; e < NEXP; e++) {
      lc[e] = tanhf((float)(acc[e] * (1.0 / 30.0))) * 30.0f;
      mx = lc[e] > mx ? lc[e] : mx;
    }
    float s = 0.0f;
#pragma unroll
    for (int e = 0; e < NEXP; e++) { lc[e] = expf(lc[e] - mx); s += lc[e]; }
    float inv = 1.0f / s;
    top_idx[t * 2] = i0; top_idx[t * 2 + 1] = i1;
    top_w[t * 2] = lc[i0] * inv; top_w[t * 2 + 1] = lc[i1] * inv;
    atomicAdd(&counts[i0], 1);
    atomicAdd(&counts[i1], 1);
  }
}

__global__ void k_scan(const int* __restrict__ counts, int* __restrict__ offs,
                       int* __restrict__ cursor) {
  if (threadIdx.x == 0) {
    int s = 0;
    for (int e = 0; e < NEXP; e++) { offs[e] = s; cursor[e] = s; s += counts[e]; }
    offs[NEXP] = s;
  }
}

__global__ void k_scatter(const int* __restrict__ top_idx, const float* __restrict__ top_w,
                          int* __restrict__ cursor, int* __restrict__ perm_tok,
                          float* __restrict__ perm_w) {
  int t = blockIdx.x * 256 + threadIdx.x;
#pragma unroll
  for (int k = 0; k < 2; k++) {
    int e = top_idx[t * 2 + k];
    int pos = atomicAdd(&cursor[e], 1);
    perm_tok[pos] = t;
    perm_w[pos] = top_w[t * 2 + k];
  }
}

__global__ void k_cast(const float* __restrict__ x, unsigned short* __restrict__ xb) {
  size_t i = ((size_t)blockIdx.x * 256 + threadIdx.x) * 8;
  float4 a = *(const float4*)(x + i);
  float4 b = *(const float4*)(x + i + 4);
  s16x8 v;
  v[0] = (short)bf16r(a.x); v[1] = (short)bf16r(a.y);
  v[2] = (short)bf16r(a.z); v[3] = (short)bf16r(a.w);
  v[4] = (short)bf16r(b.x); v[5] = (short)bf16r(b.y);
  v[6] = (short)bf16r(b.z); v[7] = (short)bf16r(b.w);
  *(s16x8*)(xb + i) = v;
}

// --------- expert GEMM 1 (one expert): H = gelu(Xe @ Wg) * (Xe @ Wu) ---------
__global__ __launch_bounds__(256) void k_mlp1(
    const unsigned short* __restrict__ xb, const float* __restrict__ wg_e,
    const float* __restrict__ wu_e, const int* __restrict__ perm_tok,
    const int* __restrict__ offs, int e, unsigned short* __restrict__ H) {
  __shared__ char lds[3 * 16384];  // As | Bg | Bu, 128 rows x 64 bf16 each, swizzled
  char* As = lds;
  char* Bg = lds + 16384;
  char* Bu = lds + 2 * 16384;
  const int off = offs[e], cnt = offs[e + 1] - off;
  const int nb = blockIdx.x * 128;
  const int tid = threadIdx.x;
  const int lane = tid & 63;
  const int wr = tid >> 7, wc = (tid >> 6) & 1;
  const int l15 = lane & 15, lk = lane >> 4;

  for (int mt = blockIdx.y; mt * 128 < cnt; mt += 16) {
    const unsigned short* asrc[4];
#pragma unroll
    for (int r = 0; r < 4; r++) {
      int m = (tid >> 3) + 32 * r;
      int gm = mt * 128 + m;
      if (gm >= cnt) gm = cnt - 1;
      asrc[r] = xb + (size_t)perm_tok[off + gm] * DDIM + (tid & 7) * 8;
    }
    f32x4 accg[4][4], accu[4][4];
#pragma unroll
    for (int mi = 0; mi < 4; mi++)
#pragma unroll
      for (int ni = 0; ni < 4; ni++) {
        accg[mi][ni] = f32x4{0.f, 0.f, 0.f, 0.f};
        accu[mi][ni] = f32x4{0.f, 0.f, 0.f, 0.f};
      }

    for (int k0 = 0; k0 < DDIM; k0 += 64) {
      __syncthreads();
      // stage A (gathered token rows, bf16 direct)
#pragma unroll
      for (int r = 0; r < 4; r++) {
        int m = (tid >> 3) + 32 * r;
        s16x8 v = *(const s16x8*)(asrc[r] + k0);
        *(s16x8*)(As + swz16(m, (tid & 7) * 16)) = v;
      }
      // stage Bg/Bu: transpose-gather fp32 -> bf16, [n][k] layout
#pragma unroll
      for (int r = 0; r < 4; r++) {
        int flat = tid + 256 * r;
        int n = flat & 127, kg = flat >> 7;
        const float* pg = wg_e + (size_t)(k0 + kg * 8) * FDIM + (nb + n);
        const float* pu = wu_e + (size_t)(k0 + kg * 8) * FDIM + (nb + n);
        s16x8 vg, vu;
#pragma unroll
        for (int j = 0; j < 8; j++) {
          vg[j] = (short)bf16r(pg[(size_t)j * FDIM]);
          vu[j] = (short)bf16r(pu[(size_t)j * FDIM]);
        }
        int dst = swz16(n, kg * 16);
        *(s16x8*)(Bg + dst) = vg;
        *(s16x8*)(Bu + dst) = vu;
      }
      __syncthreads();
#pragma unroll
      for (int ks = 0; ks < 2; ks++) {
        s16x8 a[4];
#pragma unroll
        for (int mi = 0; mi < 4; mi++)
          a[mi] = *(const s16x8*)(As + swz16(wr * 64 + mi * 16 + l15, ks * 64 + lk * 16));
#pragma unroll
        for (int ni = 0; ni < 4; ni++) {
          int boff = swz16(wc * 64 + ni * 16 + l15, ks * 64 + lk * 16);
          s16x8 bg = *(const s16x8*)(Bg + boff);
          s16x8 bu = *(const s16x8*)(Bu + boff);
#pragma unroll
          for (int mi = 0; mi < 4; mi++) {
            accg[mi][ni] = mfma16(a[mi], bg, accg[mi][ni]);
            accu[mi][ni] = mfma16(a[mi], bu, accu[mi][ni]);
          }
        }
      }
    }
    // epilogue: h = gelu_tanh(g) * u  -> H[slot_local][F] bf16
#pragma unroll
    for (int mi = 0; mi < 4; mi++) {
      int rb = wr * 64 + mi * 16 + lk * 4;
#pragma unroll
      for (int j = 0; j < 4; j++) {
        int gm = mt * 128 + rb + j;
        if (gm < cnt) {
          unsigned short* hrow = H + (size_t)gm * FDIM + nb + wc * 64 + l15;
#pragma unroll
          for (int ni = 0; ni < 4; ni++) {
            float g = accg[mi][ni][j];
            float u = accu[mi][ni][j];
            float x3 = g * g * g;
            float gl = 0.5f * g * (1.0f + tanhf(0.7978845608f * (g + 0.044715f * x3)));
            hrow[ni * 16] = bf16r(gl * u);
          }
        }
      }
    }
  }
}

// --------- expert GEMM 2 (one expert): out += w * (He @ Wd) ------------------
__global__ __launch_bounds__(256) void k_mlp2(
    const unsigned short* __restrict__ H, const float* __restrict__ wd_e,
    const int* __restrict__ perm_tok, const float* __restrict__ perm_w,
    const int* __restrict__ offs, int e, float* __restrict__ out) {
  __shared__ char lds[2 * 16384];
  char* As = lds;
  char* Bd = lds + 16384;
  const int off = offs[e], cnt = offs[e + 1] - off;
  const int nb = blockIdx.x * 128;
  const int tid = threadIdx.x;
  const int lane = tid & 63;
  const int wr = tid >> 7, wc = (tid >> 6) & 1;
  const int l15 = lane & 15, lk = lane >> 4;

  for (int mt = blockIdx.y; mt * 128 < cnt; mt += 16) {
    const unsigned short* asrc[4];
#pragma unroll
    for (int r = 0; r < 4; r++) {
      int m = (tid >> 3) + 32 * r;
      int gm = mt * 128 + m;
      if (gm >= cnt) gm = cnt - 1;
      asrc[r] = H + (size_t)gm * FDIM + (tid & 7) * 8;
    }
    f32x4 acc[4][4];
#pragma unroll
    for (int mi = 0; mi < 4; mi++)
#pragma unroll
      for (int ni = 0; ni < 4; ni++) acc[mi][ni] = f32x4{0.f, 0.f, 0.f, 0.f};

    for (int k0 = 0; k0 < FDIM; k0 += 64) {
      __syncthreads();
#pragma unroll
      for (int r = 0; r < 4; r++) {
        int m = (tid >> 3) + 32 * r;
        s16x8 v = *(const s16x8*)(asrc[r] + k0);
        *(s16x8*)(As + swz16(m, (tid & 7) * 16)) = v;
      }
#pragma unroll
      for (int r = 0; r < 4; r++) {
        int flat = tid + 256 * r;
        int n = flat & 127, kg = flat >> 7;
        const float* pd = wd_e + (size_t)(k0 + kg * 8) * DDIM + (nb + n);
        s16x8 vd;
#pragma unroll
        for (int j = 0; j < 8; j++) vd[j] = (short)bf16r(pd[(size_t)j * DDIM]);
        *(s16x8*)(Bd + swz16(n, kg * 16)) = vd;
      }
      __syncthreads();
#pragma unroll
      for (int ks = 0; ks < 2; ks++) {
        s16x8 a[4];
#pragma unroll
        for (int mi = 0; mi < 4; mi++)
          a[mi] = *(const s16x8*)(As + swz16(wr * 64 + mi * 16 + l15, ks * 64 + lk * 16));
#pragma unroll
        for (int ni = 0; ni < 4; ni++) {
          s16x8 bd = *(const s16x8*)(Bd + swz16(wc * 64 + ni * 16 + l15, ks * 64 + lk * 16));
#pragma unroll
          for (int mi = 0; mi < 4; mi++) acc[mi][ni] = mfma16(a[mi], bd, acc[mi][ni]);
        }
      }
    }
#pragma unroll
    for (int mi = 0; mi < 4; mi++) {
      int rb = wr * 64 + mi * 16 + lk * 4;
#pragma unroll
      for (int j = 0; j < 4; j++) {
        int gm = mt * 128 + rb + j;
        if (gm < cnt) {
          int tok = perm_tok[off + gm];
          float w = perm_w[off + gm];
          float* orow = out + (size_t)tok * DDIM + nb + wc * 64 + l15;
#pragma unroll
          for (int ni = 0; ni < 4; ni++) atomicAdd(&orow[ni * 16], w * acc[mi][ni][j]);
        }
      }
    }
  }
}

extern "C" void kernel_launch(void* const* d_in, const int* in_sizes, int n_in,
                              void* d_out, int out_size, void* d_ws, size_t ws_size,
                              hipStream_t stream) {
  const float* x = (const float*)d_in[0];
  const float* gw = (const float*)d_in[1];
  const float* wgate = (const float*)d_in[2];
  const float* wup = (const float*)d_in[3];
  const float* wdown = (const float*)d_in[4];
  float* out = (float*)d_out;

  char* ws = (char*)d_ws;
  unsigned short* xb = (unsigned short*)ws;                 // 33,554,432 B
  unsigned short* H = (unsigned short*)(ws + 33554432);     // 67,108,864 B (8192 slots cap)
  char* meta = ws + 33554432 + 67108864;
  int* counts = (int*)(meta);
  int* offs = (int*)(meta + 64);
  int* cursor = (int*)(meta + 128);
  int* top_idx = (int*)(meta + 256);
  float* top_w = (float*)(meta + 256 + 65536);
  int* perm_tok = (int*)(meta + 256 + 131072);
  float* perm_w = (float*)(meta + 256 + 196608);

  hipMemsetAsync(counts, 0, 64, stream);
  hipMemsetAsync(d_out, 0, (size_t)TNUM * DDIM * 4, stream);
  k_router<<<TNUM / 4, 256, 0, stream>>>(x, gw, top_idx, top_w, counts);
  k_scan<<<1, 64, 0, stream>>>(counts, offs, cursor);
  k_scatter<<<TNUM / 256, 256, 0, stream>>>(top_idx, top_w, cursor, perm_tok, perm_w);
  k_cast<<<(TNUM * DDIM / 8) / 256, 256, 0, stream>>>(x, xb);
  for (int e = 0; e < NEXP; e++) {
    k_mlp1<<<dim3(FDIM / 128, 16), 256, 0, stream>>>(
        xb, wgate + (size_t)e * DDIM * FDIM, wup + (size_t)e * DDIM * FDIM,
        perm_tok, offs, e, H);
    k_mlp2<<<dim3(DDIM / 128, 16), 256, 0, stream>>>(
        H, wdown + (size_t)e * FDIM * DDIM, perm_tok, perm_w, offs, e, out);
  }
}

// Round 4
// 2974.803 us; speedup vs baseline: 1.0669x; 1.0669x over previous
//
#include <hip/hip_runtime.h>
#include <hip/hip_bf16.h>
#include <cstdint>
#include <cstddef>

#define TNUM 8192
#define DDIM 2048
#define FDIM 4096
#define NEXP 8

typedef __attribute__((ext_vector_type(4))) float f32x4;
typedef __attribute__((ext_vector_type(4))) unsigned u32x4;
typedef __attribute__((ext_vector_type(8))) short s16x8;
typedef __attribute__((ext_vector_type(8))) __bf16 bf16x8v;

__device__ inline f32x4 mfma16(s16x8 a, s16x8 b, f32x4 c) {
  return __builtin_amdgcn_mfma_f32_16x16x32_bf16(
      __builtin_bit_cast(bf16x8v, a), __builtin_bit_cast(bf16x8v, b), c, 0, 0, 0);
}

// round-to-nearest-even fp32 -> bf16 bits (scalar path)
__device__ inline unsigned short bf16r(float f) {
  union { float f; unsigned u; } x; x.f = f;
  unsigned r = x.u + 0x7fffu + ((x.u >> 16) & 1u);
  return (unsigned short)(r >> 16);
}

// packed pair fp32->bf16 RNE (compiler fuses to v_cvt_pk_bf16_f32)
__device__ inline unsigned pk2(float a, float b) {
  __hip_bfloat162 h = __float22bfloat162_rn(make_float2(a, b));
  unsigned r;
  __builtin_memcpy(&r, &h, 4);
  return r;
}

// XOR swizzle within 128-byte rows: bijective per row, same fn on write+read
__device__ inline int swz16(int row, int b) {
  return (row << 7) + (b ^ ((row & 7) << 4));
}

// ---------------- router: fp64 logits, top-2 on logits, fp32 softmax values --
__global__ __launch_bounds__(256) void k_router(
    const float* __restrict__ x, const float* __restrict__ gw,
    int* __restrict__ top_idx, float* __restrict__ top_w, int* __restrict__ counts) {
  __shared__ float gwT[NEXP][DDIM];  // 64KB, transposed for conflict-free reads
  const int tid = threadIdx.x;
  for (int i = tid; i < NEXP * DDIM; i += 256) {
    int d = i >> 3, e = i & 7;
    gwT[e][d] = gw[i];
  }
  __syncthreads();
  const int lane = tid & 63;
  const int t = blockIdx.x * 4 + (tid >> 6);
  const float4* xr = (const float4*)(x + (size_t)t * DDIM);
  double acc[NEXP];
#pragma unroll
  for (int e = 0; e < NEXP; e++) acc[e] = 0.0;
  for (int d4 = lane; d4 < DDIM / 4; d4 += 64) {
    float4 xv = xr[d4];
#pragma unroll
    for (int e = 0; e < NEXP; e++) {
      float4 gv = *(const float4*)&gwT[e][d4 * 4];
      acc[e] += (double)xv.x * gv.x + (double)xv.y * gv.y +
                (double)xv.z * gv.z + (double)xv.w * gv.w;
    }
  }
#pragma unroll
  for (int e = 0; e < NEXP; e++) {
    double v = acc[e];
#pragma unroll
    for (int s = 32; s > 0; s >>= 1) v += __shfl_xor(v, s);
    acc[e] = v;
  }
  if (lane == 0) {
    // top-2 by fp64 logits (softcap+softmax monotonic; ties -> lowest idx)
    int i0 = 0; double b0 = acc[0];
#pragma unroll
    for (int e = 1; e < NEXP; e++) if (acc[e] > b0) { b0 = acc[e]; i0 = e; }
    int i1 = (i0 == 0) ? 1 : 0; double b1 = acc[i1];
#pragma unroll
    for (int e = 0; e < NEXP; e++) {
      if (e == i0 || e == i1) continue;
      if (acc[e] > b1) { b1 = acc[e]; i1 = e; }
    }
    float lc[NEXP]; float mx = -1e30f;
#pragma unroll
    for (int e = 0; e < NEXP; e++) {
      lc[e] = tanhf((float)(acc[e] * (1.0 / 30.0))) * 30.0f;
      mx = lc[e] > mx ? lc[e] : mx;
    }
    float s = 0.0f;
#pragma unroll
    for (int e = 0; e < NEXP; e++) { lc[e] = expf(lc[e] - mx); s += lc[e]; }
    float inv = 1.0f / s;
    top_idx[t * 2] = i0; top_idx[t * 2 + 1] = i1;
    top_w[t * 2] = lc[i0] * inv; top_w[t * 2 + 1] = lc[i1] * inv;
    atomicAdd(&counts[i0], 1);
    atomicAdd(&counts[i1], 1);
  }
}

__global__ void k_scan(const int* __restrict__ counts, int* __restrict__ offs,
                       int* __restrict__ cursor) {
  if (threadIdx.x == 0) {
    int s = 0;
    for (int e = 0; e < NEXP; e++) { offs[e] = s; cursor[e] = s; s += counts[e]; }
    offs[NEXP] = s;
  }
}

__global__ void k_scatter(const int* __restrict__ top_idx, const float* __restrict__ top_w,
                          int* __restrict__ cursor, int* __restrict__ perm_tok,
                          float* __restrict__ perm_w) {
  int t = blockIdx.x * 256 + threadIdx.x;
#pragma unroll
  for (int k = 0; k < 2; k++) {
    int e = top_idx[t * 2 + k];
    int pos = atomicAdd(&cursor[e], 1);
    perm_tok[pos] = t;
    perm_w[pos] = top_w[t * 2 + k];
  }
}

__global__ void k_cast(const float* __restrict__ x, unsigned short* __restrict__ xb) {
  size_t i = ((size_t)blockIdx.x * 256 + threadIdx.x) * 8;
  f32x4 a = *(const f32x4*)(x + i);
  f32x4 b = *(const f32x4*)(x + i + 4);
  u32x4 v;
  v[0] = pk2(a[0], a[1]); v[1] = pk2(a[2], a[3]);
  v[2] = pk2(b[0], b[1]); v[3] = pk2(b[2], b[3]);
  *(u32x4*)(xb + i) = v;
}

// stage one 64k x 128n fp32 weight tile -> bf16 [n][k] swizzled LDS
// thread: kb = tid&7 (k-group of 8), n4 = tid>>3 (n-group of 4)
__device__ inline void stage_w(const float* __restrict__ W, int ldb, int k0, int nb,
                               char* __restrict__ B, int tid) {
  const int kb = tid & 7, n4 = tid >> 3;
  const float* p = W + (size_t)(k0 + kb * 8) * ldb + nb + n4 * 4;
  f32x4 wv[8];
#pragma unroll
  for (int i = 0; i < 8; i++) wv[i] = *(const f32x4*)(p + (size_t)i * ldb);
#pragma unroll
  for (int jn = 0; jn < 4; jn++) {
    u32x4 row;
#pragma unroll
    for (int t = 0; t < 4; t++) row[t] = pk2(wv[2 * t][jn], wv[2 * t + 1][jn]);
    *(s16x8*)(B + swz16(n4 * 4 + jn, kb * 16)) = __builtin_bit_cast(s16x8, row);
  }
}

// --------- expert GEMM 1: H = gelu(Xe @ Wg) * (Xe @ Wu), bf16 out ------------
__global__ __launch_bounds__(256) void k_mlp1(
    const unsigned short* __restrict__ xb, const float* __restrict__ wgate,
    const float* __restrict__ wup, const int* __restrict__ perm_tok,
    const int* __restrict__ offs, int e0, int hmask, unsigned short* __restrict__ H) {
  __shared__ char lds[3 * 16384];  // As | Bg | Bu, 128 rows x 64 bf16 each, swizzled
  char* As = lds;
  char* Bg = lds + 16384;
  char* Bu = lds + 2 * 16384;
  const int e = e0 + blockIdx.z;
  const int off = offs[e], cnt = offs[e + 1] - off;
  const int hbase = off & hmask;
  const int nb = blockIdx.x * 128;
  const float* wg_e = wgate + (size_t)e * DDIM * FDIM;
  const float* wu_e = wup + (size_t)e * DDIM * FDIM;
  const int tid = threadIdx.x;
  const int lane = tid & 63;
  const int wr = tid >> 7, wc = (tid >> 6) & 1;
  const int l15 = lane & 15, lk = lane >> 4;

  for (int mt = blockIdx.y; mt * 128 < cnt; mt += 16) {
    const unsigned short* asrc[4];
#pragma unroll
    for (int r = 0; r < 4; r++) {
      int m = (tid >> 3) + 32 * r;
      int gm = mt * 128 + m;
      if (gm >= cnt) gm = cnt - 1;
      asrc[r] = xb + (size_t)perm_tok[off + gm] * DDIM + (tid & 7) * 8;
    }
    f32x4 accg[4][4], accu[4][4];
#pragma unroll
    for (int mi = 0; mi < 4; mi++)
#pragma unroll
      for (int ni = 0; ni < 4; ni++) {
        accg[mi][ni] = f32x4{0.f, 0.f, 0.f, 0.f};
        accu[mi][ni] = f32x4{0.f, 0.f, 0.f, 0.f};
      }

    for (int k0 = 0; k0 < DDIM; k0 += 64) {
      __syncthreads();
#pragma unroll
      for (int r = 0; r < 4; r++) {
        int m = (tid >> 3) + 32 * r;
        s16x8 v = *(const s16x8*)(asrc[r] + k0);
        *(s16x8*)(As + swz16(m, (tid & 7) * 16)) = v;
      }
      stage_w(wg_e, FDIM, k0, nb, Bg, tid);
      stage_w(wu_e, FDIM, k0, nb, Bu, tid);
      __syncthreads();
#pragma unroll
      for (int ks = 0; ks < 2; ks++) {
        s16x8 a[4];
#pragma unroll
        for (int mi = 0; mi < 4; mi++)
          a[mi] = *(const s16x8*)(As + swz16(wr * 64 + mi * 16 + l15, ks * 64 + lk * 16));
#pragma unroll
        for (int ni = 0; ni < 4; ni++) {
          int boff = swz16(wc * 64 + ni * 16 + l15, ks * 64 + lk * 16);
          s16x8 bg = *(const s16x8*)(Bg + boff);
          s16x8 bu = *(const s16x8*)(Bu + boff);
#pragma unroll
          for (int mi = 0; mi < 4; mi++) {
            accg[mi][ni] = mfma16(a[mi], bg, accg[mi][ni]);
            accu[mi][ni] = mfma16(a[mi], bu, accu[mi][ni]);
          }
        }
      }
    }
    // epilogue: h = gelu_tanh(g) * u  -> H[hbase+gm][F] bf16
#pragma unroll
    for (int mi = 0; mi < 4; mi++) {
      int rb = wr * 64 + mi * 16 + lk * 4;
#pragma unroll
      for (int j = 0; j < 4; j++) {
        int gm = mt * 128 + rb + j;
        if (gm < cnt) {
          unsigned short* hrow = H + (size_t)(hbase + gm) * FDIM + nb + wc * 64 + l15;
#pragma unroll
          for (int ni = 0; ni < 4; ni++) {
            float g = accg[mi][ni][j];
            float u = accu[mi][ni][j];
            float x3 = g * g * g;
            float gl = 0.5f * g * (1.0f + tanhf(0.7978845608f * (g + 0.044715f * x3)));
            hrow[ni * 16] = bf16r(gl * u);
          }
        }
      }
    }
  }
}

// --------- expert GEMM 2: out += w * (He @ Wd), fp32 atomic scatter ----------
__global__ __launch_bounds__(256) void k_mlp2(
    const unsigned short* __restrict__ H, const float* __restrict__ wdown,
    const int* __restrict__ perm_tok, const float* __restrict__ perm_w,
    const int* __restrict__ offs, int e0, int hmask, float* __restrict__ out) {
  __shared__ char lds[2 * 16384];
  char* As = lds;
  char* Bd = lds + 16384;
  const int e = e0 + blockIdx.z;
  const int off = offs[e], cnt = offs[e + 1] - off;
  const int hbase = off & hmask;
  const int nb = blockIdx.x * 128;
  const float* wd_e = wdown + (size_t)e * FDIM * DDIM;
  const int tid = threadIdx.x;
  const int lane = tid & 63;
  const int wr = tid >> 7, wc = (tid >> 6) & 1;
  const int l15 = lane & 15, lk = lane >> 4;

  for (int mt = blockIdx.y; mt * 128 < cnt; mt += 16) {
    const unsigned short* asrc[4];
#pragma unroll
    for (int r = 0; r < 4; r++) {
      int m = (tid >> 3) + 32 * r;
      int gm = mt * 128 + m;
      if (gm >= cnt) gm = cnt - 1;
      asrc[r] = H + (size_t)(hbase + gm) * FDIM + (tid & 7) * 8;
    }
    f32x4 acc[4][4];
#pragma unroll
    for (int mi = 0; mi < 4; mi++)
#pragma unroll
      for (int ni = 0; ni < 4; ni++) acc[mi][ni] = f32x4{0.f, 0.f, 0.f, 0.f};

    for (int k0 = 0; k0 < FDIM; k0 += 64) {
      __syncthreads();
#pragma unroll
      for (int r = 0; r < 4; r++) {
        int m = (tid >> 3) + 32 * r;
        s16x8 v = *(const s16x8*)(asrc[r] + k0);
        *(s16x8*)(As + swz16(m, (tid & 7) * 16)) = v;
      }
      stage_w(wd_e, DDIM, k0, nb, Bd, tid);
      __syncthreads();
#pragma unroll
      for (int ks = 0; ks < 2; ks++) {
        s16x8 a[4];
#pragma unroll
        for (int mi = 0; mi < 4; mi++)
          a[mi] = *(const s16x8*)(As + swz16(wr * 64 + mi * 16 + l15, ks * 64 + lk * 16));
#pragma unroll
        for (int ni = 0; ni < 4; ni++) {
          s16x8 bd = *(const s16x8*)(Bd + swz16(wc * 64 + ni * 16 + l15, ks * 64 + lk * 16));
#pragma unroll
          for (int mi = 0; mi < 4; mi++) acc[mi][ni] = mfma16(a[mi], bd, acc[mi][ni]);
        }
      }
    }
#pragma unroll
    for (int mi = 0; mi < 4; mi++) {
      int rb = wr * 64 + mi * 16 + lk * 4;
#pragma unroll
      for (int j = 0; j < 4; j++) {
        int gm = mt * 128 + rb + j;
        if (gm < cnt) {
          int tok = perm_tok[off + gm];
          float w = perm_w[off + gm];
          float* orow = out + (size_t)tok * DDIM + nb + wc * 64 + l15;
#pragma unroll
          for (int ni = 0; ni < 4; ni++) atomicAdd(&orow[ni * 16], w * acc[mi][ni][j]);
        }
      }
    }
  }
}

extern "C" void kernel_launch(void* const* d_in, const int* in_sizes, int n_in,
                              void* d_out, int out_size, void* d_ws, size_t ws_size,
                              hipStream_t stream) {
  const float* x = (const float*)d_in[0];
  const float* gw = (const float*)d_in[1];
  const float* wgate = (const float*)d_in[2];
  const float* wup = (const float*)d_in[3];
  const float* wdown = (const float*)d_in[4];
  float* out = (float*)d_out;

  // big path: xb 32MB + H(16384 slots) 128MB + meta; small path: H(8192) 64MB
  const size_t XB_B = 33554432;
  const size_t H_BIG = 134217728, H_SMALL = 67108864;
  const bool big = ws_size >= XB_B + H_BIG + 524288;

  char* ws = (char*)d_ws;
  unsigned short* xb = (unsigned short*)ws;
  unsigned short* H = (unsigned short*)(ws + XB_B);
  char* meta = ws + XB_B + (big ? H_BIG : H_SMALL);
  int* counts = (int*)(meta);
  int* offs = (int*)(meta + 64);
  int* cursor = (int*)(meta + 128);
  int* top_idx = (int*)(meta + 256);
  float* top_w = (float*)(meta + 256 + 65536);
  int* perm_tok = (int*)(meta + 256 + 131072);
  float* perm_w = (float*)(meta + 256 + 196608);

  (void)hipMemsetAsync(counts, 0, 64, stream);
  (void)hipMemsetAsync(d_out, 0, (size_t)TNUM * DDIM * 4, stream);
  k_router<<<TNUM / 4, 256, 0, stream>>>(x, gw, top_idx, top_w, counts);
  k_scan<<<1, 64, 0, stream>>>(counts, offs, cursor);
  k_scatter<<<TNUM / 256, 256, 0, stream>>>(top_idx, top_w, cursor, perm_tok, perm_w);
  k_cast<<<(TNUM * DDIM / 8) / 256, 256, 0, stream>>>(x, xb);
  if (big) {
    k_mlp1<<<dim3(FDIM / 128, 16, NEXP), 256, 0, stream>>>(
        xb, wgate, wup, perm_tok, offs, 0, -1, H);
    k_mlp2<<<dim3(DDIM / 128, 16, NEXP), 256, 0, stream>>>(
        H, wdown, perm_tok, perm_w, offs, 0, -1, out);
  } else {
    for (int e = 0; e < NEXP; e++) {
      k_mlp1<<<dim3(FDIM / 128, 16, 1), 256, 0, stream>>>(
          xb, wgate, wup, perm_tok, offs, e, 0, H);
      k_mlp2<<<dim3(DDIM / 128, 16, 1), 256, 0, stream>>>(
          H, wdown, perm_tok, perm_w, offs, e, 0, out);
    }
  }
}

// Round 5
// 2114.503 us; speedup vs baseline: 1.5010x; 1.4069x over previous
//
#include <hip/hip_runtime.h>
#include <hip/hip_bf16.h>
#include <cstdint>
#include <cstddef>

#define TNUM 8192
#define DDIM 2048
#define FDIM 4096
#define NEXP 8

typedef __attribute__((ext_vector_type(4))) float f32x4;
typedef __attribute__((ext_vector_type(4))) unsigned u32x4;
typedef __attribute__((ext_vector_type(8))) short s16x8;
typedef __attribute__((ext_vector_type(8))) __bf16 bf16x8v;

__device__ inline f32x4 mfma16(s16x8 a, s16x8 b, f32x4 c) {
  return __builtin_amdgcn_mfma_f32_16x16x32_bf16(
      __builtin_bit_cast(bf16x8v, a), __builtin_bit_cast(bf16x8v, b), c, 0, 0, 0);
}

// round-to-nearest-even fp32 -> bf16 bits (scalar path)
__device__ inline unsigned short bf16r(float f) {
  union { float f; unsigned u; } x; x.f = f;
  unsigned r = x.u + 0x7fffu + ((x.u >> 16) & 1u);
  return (unsigned short)(r >> 16);
}

// packed pair fp32->bf16 RNE (compiler fuses to v_cvt_pk_bf16_f32)
__device__ inline unsigned pk2(float a, float b) {
  __hip_bfloat162 h = __float22bfloat162_rn(make_float2(a, b));
  unsigned r;
  __builtin_memcpy(&r, &h, 4);
  return r;
}

// XOR swizzle within 128-byte rows: bijective per row, same fn on write+read
__device__ inline int swz16(int row, int b) {
  return (row << 7) + (b ^ ((row & 7) << 4));
}

// async global->LDS, 16B per lane; lds base must be wave-uniform
typedef const __attribute__((address_space(1))) void* gp_t;
typedef __attribute__((address_space(3))) void* lp_t;
__device__ inline void gl16(const void* g, void* l) {
  __builtin_amdgcn_global_load_lds((gp_t)g, (lp_t)l, 16, 0, 0);
}

// ---------------- router: fp64 logits, top-2 on logits, fp32 softmax values --
__global__ __launch_bounds__(256) void k_router(
    const float* __restrict__ x, const float* __restrict__ gw,
    int* __restrict__ top_idx, float* __restrict__ top_w, int* __restrict__ counts) {
  __shared__ float gwT[NEXP][DDIM];  // 64KB, transposed for conflict-free reads
  const int tid = threadIdx.x;
  for (int i = tid; i < NEXP * DDIM; i += 256) {
    int d = i >> 3, e = i & 7;
    gwT[e][d] = gw[i];
  }
  __syncthreads();
  const int lane = tid & 63;
  const int t = blockIdx.x * 4 + (tid >> 6);
  const float4* xr = (const float4*)(x + (size_t)t * DDIM);
  double acc[NEXP];
#pragma unroll
  for (int e = 0; e < NEXP; e++) acc[e] = 0.0;
  for (int d4 = lane; d4 < DDIM / 4; d4 += 64) {
    float4 xv = xr[d4];
#pragma unroll
    for (int e = 0; e < NEXP; e++) {
      float4 gv = *(const float4*)&gwT[e][d4 * 4];
      acc[e] += (double)xv.x * gv.x + (double)xv.y * gv.y +
                (double)xv.z * gv.z + (double)xv.w * gv.w;
    }
  }
#pragma unroll
  for (int e = 0; e < NEXP; e++) {
    double v = acc[e];
#pragma unroll
    for (int s = 32; s > 0; s >>= 1) v += __shfl_xor(v, s);
    acc[e] = v;
  }
  if (lane == 0) {
    int i0 = 0; double b0 = acc[0];
#pragma unroll
    for (int e = 1; e < NEXP; e++) if (acc[e] > b0) { b0 = acc[e]; i0 = e; }
    int i1 = (i0 == 0) ? 1 : 0; double b1 = acc[i1];
#pragma unroll
    for (int e = 0; e < NEXP; e++) {
      if (e == i0 || e == i1) continue;
      if (acc[e] > b1) { b1 = acc[e]; i1 = e; }
    }
    float lc[NEXP]; float mx = -1e30f;
#pragma unroll
    for (int e = 0; e < NEXP; e++) {
      lc[e] = tanhf((float)(acc[e] * (1.0 / 30.0))) * 30.0f;
      mx = lc[e] > mx ? lc[e] : mx;
    }
    float s = 0.0f;
#pragma unroll
    for (int e = 0; e < NEXP; e++) { lc[e] = expf(lc[e] - mx); s += lc[e]; }
    float inv = 1.0f / s;
    top_idx[t * 2] = i0; top_idx[t * 2 + 1] = i1;
    top_w[t * 2] = lc[i0] * inv; top_w[t * 2 + 1] = lc[i1] * inv;
    atomicAdd(&counts[i0], 1);
    atomicAdd(&counts[i1], 1);
  }
}

__global__ void k_scan(const int* __restrict__ counts, int* __restrict__ offs,
                       int* __restrict__ cursor) {
  if (threadIdx.x == 0) {
    int s = 0;
    for (int e = 0; e < NEXP; e++) { offs[e] = s; cursor[e] = s; s += counts[e]; }
    offs[NEXP] = s;
  }
}

__global__ void k_scatter(const int* __restrict__ top_idx, const float* __restrict__ top_w,
                          int* __restrict__ cursor, int* __restrict__ perm_tok,
                          float* __restrict__ perm_w) {
  int t = blockIdx.x * 256 + threadIdx.x;
#pragma unroll
  for (int k = 0; k < 2; k++) {
    int e = top_idx[t * 2 + k];
    int pos = atomicAdd(&cursor[e], 1);
    perm_tok[pos] = t;
    perm_w[pos] = top_w[t * 2 + k];
  }
}

__global__ void k_cast(const float* __restrict__ x, unsigned short* __restrict__ xb) {
  size_t i = ((size_t)blockIdx.x * 256 + threadIdx.x) * 8;
  f32x4 a = *(const f32x4*)(x + i);
  f32x4 b = *(const f32x4*)(x + i + 4);
  u32x4 v;
  v[0] = pk2(a[0], a[1]); v[1] = pk2(a[2], a[3]);
  v[2] = pk2(b[0], b[1]); v[3] = pk2(b[2], b[3]);
  *(u32x4*)(xb + i) = v;
}

// ---- one-shot: fp32 [E][K][N] -> bf16 [E][N][K] (transpose + convert) -------
__global__ __launch_bounds__(256) void k_convT(
    const float* __restrict__ src, unsigned short* __restrict__ dst, int K, int N) {
  __shared__ char ct[8192];  // 64 n-rows x 128B (64 bf16 k), XOR-swizzled
  const int e = blockIdx.z;
  const float* src_e = src + (size_t)e * K * N;
  unsigned short* dst_e = dst + (size_t)e * N * K;
  const int k0 = blockIdx.y * 64, n0 = blockIdx.x * 64;
  const int tid = threadIdx.x;
#pragma unroll
  for (int i = 0; i < 4; i++) {
    int idx = tid + i * 256;          // 0..1023
    int kr = idx >> 4, f4 = idx & 15; // kr 0..63, f4 0..15
    f32x4 v = *(const f32x4*)(src_e + (size_t)(k0 + kr) * N + n0 + f4 * 4);
#pragma unroll
    for (int j = 0; j < 4; j++) {
      int n = f4 * 4 + j;
      *(unsigned short*)(ct + n * 128 + ((kr * 2) ^ ((n & 7) << 4))) = bf16r(v[j]);
    }
  }
  __syncthreads();
#pragma unroll
  for (int i = 0; i < 2; i++) {
    int s = tid + i * 256;            // 0..511
    int n = s >> 3, ks = s & 7;
    s16x8 val = *(const s16x8*)(ct + n * 128 + ((ks * 16) ^ ((n & 7) << 4)));
    *(s16x8*)(dst_e + (size_t)(n0 + n) * K + k0 + ks * 8) = val;
  }
}

// ======== big2 path: global_load_lds GEMMs over preconverted bf16 ============
// LDS linear dest; source pre-swizzled (kp ^= row&7) so swz16 reads stay valid.
__global__ __launch_bounds__(256) void k_mlp1_gl(
    const unsigned short* __restrict__ xb, const unsigned short* __restrict__ wgT,
    const unsigned short* __restrict__ wuT, const int* __restrict__ perm_tok,
    const int* __restrict__ offs, unsigned short* __restrict__ H) {
  __shared__ char lds[3 * 16384];
  char* As = lds;
  char* Bg = lds + 16384;
  char* Bu = lds + 32768;
  const int e = blockIdx.z;
  const int off = offs[e], cnt = offs[e + 1] - off;
  const int nb = blockIdx.x * 128;
  const unsigned short* wg_e = wgT + (size_t)e * DDIM * FDIM;  // [n=F][k=D]
  const unsigned short* wu_e = wuT + (size_t)e * DDIM * FDIM;
  const int tid = threadIdx.x;
  const int lane = tid & 63;
  const int wr = tid >> 7, wc = (tid >> 6) & 1;
  const int l15 = lane & 15, lk = lane >> 4;
  const int wbase = (tid >> 6) * 1024;  // wave-uniform LDS sub-base

  for (int mt = blockIdx.y; mt * 128 < cnt; mt += 16) {
    const unsigned short* asrc[4];
    const unsigned short* bgsrc[4];
    const unsigned short* busrc[4];
#pragma unroll
    for (int i = 0; i < 4; i++) {
      int seg = tid + i * 256;
      int m = seg >> 3, kp = (seg & 7) ^ (m & 7);
      int gm = mt * 128 + m;
      if (gm >= cnt) gm = cnt - 1;
      asrc[i] = xb + (size_t)perm_tok[off + gm] * DDIM + kp * 8;
      bgsrc[i] = wg_e + (size_t)(nb + m) * DDIM + kp * 8;
      busrc[i] = wu_e + (size_t)(nb + m) * DDIM + kp * 8;
    }
    f32x4 accg[4][4], accu[4][4];
#pragma unroll
    for (int mi = 0; mi < 4; mi++)
#pragma unroll
      for (int ni = 0; ni < 4; ni++) {
        accg[mi][ni] = f32x4{0.f, 0.f, 0.f, 0.f};
        accu[mi][ni] = f32x4{0.f, 0.f, 0.f, 0.f};
      }

    for (int k0 = 0; k0 < DDIM; k0 += 64) {
      __syncthreads();
#pragma unroll
      for (int i = 0; i < 4; i++) gl16(asrc[i] + k0, As + i * 4096 + wbase);
#pragma unroll
      for (int i = 0; i < 4; i++) gl16(bgsrc[i] + k0, Bg + i * 4096 + wbase);
#pragma unroll
      for (int i = 0; i < 4; i++) gl16(busrc[i] + k0, Bu + i * 4096 + wbase);
      __syncthreads();
#pragma unroll
      for (int ks = 0; ks < 2; ks++) {
        s16x8 a[4];
#pragma unroll
        for (int mi = 0; mi < 4; mi++)
          a[mi] = *(const s16x8*)(As + swz16(wr * 64 + mi * 16 + l15, ks * 64 + lk * 16));
#pragma unroll
        for (int ni = 0; ni < 4; ni++) {
          int boff = swz16(wc * 64 + ni * 16 + l15, ks * 64 + lk * 16);
          s16x8 bg = *(const s16x8*)(Bg + boff);
          s16x8 bu = *(const s16x8*)(Bu + boff);
#pragma unroll
          for (int mi = 0; mi < 4; mi++) {
            accg[mi][ni] = mfma16(a[mi], bg, accg[mi][ni]);
            accu[mi][ni] = mfma16(a[mi], bu, accu[mi][ni]);
          }
        }
      }
    }
#pragma unroll
    for (int mi = 0; mi < 4; mi++) {
      int rb = wr * 64 + mi * 16 + lk * 4;
#pragma unroll
      for (int j = 0; j < 4; j++) {
        int gm = mt * 128 + rb + j;
        if (gm < cnt) {
          unsigned short* hrow = H + (size_t)(off + gm) * FDIM + nb + wc * 64 + l15;
#pragma unroll
          for (int ni = 0; ni < 4; ni++) {
            float g = accg[mi][ni][j];
            float u = accu[mi][ni][j];
            float x3 = g * g * g;
            float gl = 0.5f * g * (1.0f + tanhf(0.7978845608f * (g + 0.044715f * x3)));
            hrow[ni * 16] = bf16r(gl * u);
          }
        }
      }
    }
  }
}

__global__ __launch_bounds__(256) void k_mlp2_gl(
    const unsigned short* __restrict__ H, const unsigned short* __restrict__ wdT,
    const int* __restrict__ perm_tok, const float* __restrict__ perm_w,
    const int* __restrict__ offs, float* __restrict__ out) {
  __shared__ char lds[2 * 16384];
  char* As = lds;
  char* Bd = lds + 16384;
  const int e = blockIdx.z;
  const int off = offs[e], cnt = offs[e + 1] - off;
  const int nb = blockIdx.x * 128;
  const unsigned short* wd_e = wdT + (size_t)e * FDIM * DDIM;  // [n=D][k=F]
  const int tid = threadIdx.x;
  const int lane = tid & 63;
  const int wr = tid >> 7, wc = (tid >> 6) & 1;
  const int l15 = lane & 15, lk = lane >> 4;
  const int wbase = (tid >> 6) * 1024;

  for (int mt = blockIdx.y; mt * 128 < cnt; mt += 16) {
    const unsigned short* asrc[4];
    const unsigned short* bdsrc[4];
#pragma unroll
    for (int i = 0; i < 4; i++) {
      int seg = tid + i * 256;
      int m = seg >> 3, kp = (seg & 7) ^ (m & 7);
      int gm = mt * 128 + m;
      if (gm >= cnt) gm = cnt - 1;
      asrc[i] = H + (size_t)(off + gm) * FDIM + kp * 8;
      bdsrc[i] = wd_e + (size_t)(nb + m) * FDIM + kp * 8;
    }
    f32x4 acc[4][4];
#pragma unroll
    for (int mi = 0; mi < 4; mi++)
#pragma unroll
      for (int ni = 0; ni < 4; ni++) acc[mi][ni] = f32x4{0.f, 0.f, 0.f, 0.f};

    for (int k0 = 0; k0 < FDIM; k0 += 64) {
      __syncthreads();
#pragma unroll
      for (int i = 0; i < 4; i++) gl16(asrc[i] + k0, As + i * 4096 + wbase);
#pragma unroll
      for (int i = 0; i < 4; i++) gl16(bdsrc[i] + k0, Bd + i * 4096 + wbase);
      __syncthreads();
#pragma unroll
      for (int ks = 0; ks < 2; ks++) {
        s16x8 a[4];
#pragma unroll
        for (int mi = 0; mi < 4; mi++)
          a[mi] = *(const s16x8*)(As + swz16(wr * 64 + mi * 16 + l15, ks * 64 + lk * 16));
#pragma unroll
        for (int ni = 0; ni < 4; ni++) {
          s16x8 bd = *(const s16x8*)(Bd + swz16(wc * 64 + ni * 16 + l15, ks * 64 + lk * 16));
#pragma unroll
          for (int mi = 0; mi < 4; mi++) acc[mi][ni] = mfma16(a[mi], bd, acc[mi][ni]);
        }
      }
    }
#pragma unroll
    for (int mi = 0; mi < 4; mi++) {
      int rb = wr * 64 + mi * 16 + lk * 4;
#pragma unroll
      for (int j = 0; j < 4; j++) {
        int gm = mt * 128 + rb + j;
        if (gm < cnt) {
          int tok = perm_tok[off + gm];
          float w = perm_w[off + gm];
          float* orow = out + (size_t)tok * DDIM + nb + wc * 64 + l15;
#pragma unroll
          for (int ni = 0; ni < 4; ni++) atomicAdd(&orow[ni * 16], w * acc[mi][ni][j]);
        }
      }
    }
  }
}

// ======== fallback (round-4) kernels: fp32 weights staged per K-step =========
__device__ inline void stage_w(const float* __restrict__ W, int ldb, int k0, int nb,
                               char* __restrict__ B, int tid) {
  const int kb = tid & 7, n4 = tid >> 3;
  const float* p = W + (size_t)(k0 + kb * 8) * ldb + nb + n4 * 4;
  f32x4 wv[8];
#pragma unroll
  for (int i = 0; i < 8; i++) wv[i] = *(const f32x4*)(p + (size_t)i * ldb);
#pragma unroll
  for (int jn = 0; jn < 4; jn++) {
    u32x4 row;
#pragma unroll
    for (int t = 0; t < 4; t++) row[t] = pk2(wv[2 * t][jn], wv[2 * t + 1][jn]);
    *(s16x8*)(B + swz16(n4 * 4 + jn, kb * 16)) = __builtin_bit_cast(s16x8, row);
  }
}

__global__ __launch_bounds__(256) void k_mlp1_fb(
    const unsigned short* __restrict__ xb, const float* __restrict__ wgate,
    const float* __restrict__ wup, const int* __restrict__ perm_tok,
    const int* __restrict__ offs, int e0, int hmask, unsigned short* __restrict__ H) {
  __shared__ char lds[3 * 16384];
  char* As = lds;
  char* Bg = lds + 16384;
  char* Bu = lds + 2 * 16384;
  const int e = e0 + blockIdx.z;
  const int off = offs[e], cnt = offs[e + 1] - off;
  const int hbase = off & hmask;
  const int nb = blockIdx.x * 128;
  const float* wg_e = wgate + (size_t)e * DDIM * FDIM;
  const float* wu_e = wup + (size_t)e * DDIM * FDIM;
  const int tid = threadIdx.x;
  const int lane = tid & 63;
  const int wr = tid >> 7, wc = (tid >> 6) & 1;
  const int l15 = lane & 15, lk = lane >> 4;

  for (int mt = blockIdx.y; mt * 128 < cnt; mt += 16) {
    const unsigned short* asrc[4];
#pragma unroll
    for (int r = 0; r < 4; r++) {
      int m = (tid >> 3) + 32 * r;
      int gm = mt * 128 + m;
      if (gm >= cnt) gm = cnt - 1;
      asrc[r] = xb + (size_t)perm_tok[off + gm] * DDIM + (tid & 7) * 8;
    }
    f32x4 accg[4][4], accu[4][4];
#pragma unroll
    for (int mi = 0; mi < 4; mi++)
#pragma unroll
      for (int ni = 0; ni < 4; ni++) {
        accg[mi][ni] = f32x4{0.f, 0.f, 0.f, 0.f};
        accu[mi][ni] = f32x4{0.f, 0.f, 0.f, 0.f};
      }
    for (int k0 = 0; k0 < DDIM; k0 += 64) {
      __syncthreads();
#pragma unroll
      for (int r = 0; r < 4; r++) {
        int m = (tid >> 3) + 32 * r;
        s16x8 v = *(const s16x8*)(asrc[r] + k0);
        *(s16x8*)(As + swz16(m, (tid & 7) * 16)) = v;
      }
      stage_w(wg_e, FDIM, k0, nb, Bg, tid);
      stage_w(wu_e, FDIM, k0, nb, Bu, tid);
      __syncthreads();
#pragma unroll
      for (int ks = 0; ks < 2; ks++) {
        s16x8 a[4];
#pragma unroll
        for (int mi = 0; mi < 4; mi++)
          a[mi] = *(const s16x8*)(As + swz16(wr * 64 + mi * 16 + l15, ks * 64 + lk * 16));
#pragma unroll
        for (int ni = 0; ni < 4; ni++) {
          int boff = swz16(wc * 64 + ni * 16 + l15, ks * 64 + lk * 16);
          s16x8 bg = *(const s16x8*)(Bg + boff);
          s16x8 bu = *(const s16x8*)(Bu + boff);
#pragma unroll
          for (int mi = 0; mi < 4; mi++) {
            accg[mi][ni] = mfma16(a[mi], bg, accg[mi][ni]);
            accu[mi][ni] = mfma16(a[mi], bu, accu[mi][ni]);
          }
        }
      }
    }
#pragma unroll
    for (int mi = 0; mi < 4; mi++) {
      int rb = wr * 64 + mi * 16 + lk * 4;
#pragma unroll
      for (int j = 0; j < 4; j++) {
        int gm = mt * 128 + rb + j;
        if (gm < cnt) {
          unsigned short* hrow = H + (size_t)(hbase + gm) * FDIM + nb + wc * 64 + l15;
#pragma unroll
          for (int ni = 0; ni < 4; ni++) {
            float g = accg[mi][ni][j];
            float u = accu[mi][ni][j];
            float x3 = g * g * g;
            float gl = 0.5f * g * (1.0f + tanhf(0.7978845608f * (g + 0.044715f * x3)));
            hrow[ni * 16] = bf16r(gl * u);
          }
        }
      }
    }
  }
}

__global__ __launch_bounds__(256) void k_mlp2_fb(
    const unsigned short* __restrict__ H, const float* __restrict__ wdown,
    const int* __restrict__ perm_tok, const float* __restrict__ perm_w,
    const int* __restrict__ offs, int e0, int hmask, float* __restrict__ out) {
  __shared__ char lds[2 * 16384];
  char* As = lds;
  char* Bd = lds + 16384;
  const int e = e0 + blockIdx.z;
  const int off = offs[e], cnt = offs[e + 1] - off;
  const int hbase = off & hmask;
  const int nb = blockIdx.x * 128;
  const float* wd_e = wdown + (size_t)e * FDIM * DDIM;
  const int tid = threadIdx.x;
  const int lane = tid & 63;
  const int wr = tid >> 7, wc = (tid >> 6) & 1;
  const int l15 = lane & 15, lk = lane >> 4;

  for (int mt = blockIdx.y; mt * 128 < cnt; mt += 16) {
    const unsigned short* asrc[4];
#pragma unroll
    for (int r = 0; r < 4; r++) {
      int m = (tid >> 3) + 32 * r;
      int gm = mt * 128 + m;
      if (gm >= cnt) gm = cnt - 1;
      asrc[r] = H + (size_t)(hbase + gm) * FDIM + (tid & 7) * 8;
    }
    f32x4 acc[4][4];
#pragma unroll
    for (int mi = 0; mi < 4; mi++)
#pragma unroll
      for (int ni = 0; ni < 4; ni++) acc[mi][ni] = f32x4{0.f, 0.f, 0.f, 0.f};
    for (int k0 = 0; k0 < FDIM; k0 += 64) {
      __syncthreads();
#pragma unroll
      for (int r = 0; r < 4; r++) {
        int m = (tid >> 3) + 32 * r;
        s16x8 v = *(const s16x8*)(asrc[r] + k0);
        *(s16x8*)(As + swz16(m, (tid & 7) * 16)) = v;
      }
      stage_w(wd_e, DDIM, k0, nb, Bd, tid);
      __syncthreads();
#pragma unroll
      for (int ks = 0; ks < 2; ks++) {
        s16x8 a[4];
#pragma unroll
        for (int mi = 0; mi < 4; mi++)
          a[mi] = *(const s16x8*)(As + swz16(wr * 64 + mi * 16 + l15, ks * 64 + lk * 16));
#pragma unroll
        for (int ni = 0; ni < 4; ni++) {
          s16x8 bd = *(const s16x8*)(Bd + swz16(wc * 64 + ni * 16 + l15, ks * 64 + lk * 16));
#pragma unroll
          for (int mi = 0; mi < 4; mi++) acc[mi][ni] = mfma16(a[mi], bd, acc[mi][ni]);
        }
      }
    }
#pragma unroll
    for (int mi = 0; mi < 4; mi++) {
      int rb = wr * 64 + mi * 16 + lk * 4;
#pragma unroll
      for (int j = 0; j < 4; j++) {
        int gm = mt * 128 + rb + j;
        if (gm < cnt) {
          int tok = perm_tok[off + gm];
          float w = perm_w[off + gm];
          float* orow = out + (size_t)tok * DDIM + nb + wc * 64 + l15;
#pragma unroll
          for (int ni = 0; ni < 4; ni++) atomicAdd(&orow[ni * 16], w * acc[mi][ni][j]);
        }
      }
    }
  }
}

extern "C" void kernel_launch(void* const* d_in, const int* in_sizes, int n_in,
                              void* d_out, int out_size, void* d_ws, size_t ws_size,
                              hipStream_t stream) {
  const float* x = (const float*)d_in[0];
  const float* gw = (const float*)d_in[1];
  const float* wgate = (const float*)d_in[2];
  const float* wup = (const float*)d_in[3];
  const float* wdown = (const float*)d_in[4];
  float* out = (float*)d_out;

  const size_t XB_B = 33554432;            // xb bf16
  const size_t H_BIG = 134217728;          // 16384 x 4096 bf16
  const size_t H_SMALL = 67108864;
  const size_t WT_B = 134217728;           // one weight tensor bf16
  const size_t BIG2 = XB_B + H_BIG + 3 * WT_B + 524288;   // 570,949,632
  const bool big2 = ws_size >= BIG2;
  const bool big = ws_size >= XB_B + H_BIG + 524288;

  char* ws = (char*)d_ws;
  unsigned short* xb = (unsigned short*)ws;
  unsigned short* H = (unsigned short*)(ws + XB_B);
  unsigned short* wgT = (unsigned short*)(ws + XB_B + H_BIG);
  unsigned short* wuT = (unsigned short*)(ws + XB_B + H_BIG + WT_B);
  unsigned short* wdT = (unsigned short*)(ws + XB_B + H_BIG + 2 * WT_B);
  char* meta = big2 ? (ws + XB_B + H_BIG + 3 * WT_B)
                    : (ws + XB_B + (big ? H_BIG : H_SMALL));
  int* counts = (int*)(meta);
  int* offs = (int*)(meta + 64);
  int* cursor = (int*)(meta + 128);
  int* top_idx = (int*)(meta + 256);
  float* top_w = (float*)(meta + 256 + 65536);
  int* perm_tok = (int*)(meta + 256 + 131072);
  float* perm_w = (float*)(meta + 256 + 196608);

  (void)hipMemsetAsync(counts, 0, 64, stream);
  (void)hipMemsetAsync(d_out, 0, (size_t)TNUM * DDIM * 4, stream);
  k_router<<<TNUM / 4, 256, 0, stream>>>(x, gw, top_idx, top_w, counts);
  k_scan<<<1, 64, 0, stream>>>(counts, offs, cursor);
  k_scatter<<<TNUM / 256, 256, 0, stream>>>(top_idx, top_w, cursor, perm_tok, perm_w);
  k_cast<<<(TNUM * DDIM / 8) / 256, 256, 0, stream>>>(x, xb);
  if (big2) {
    k_convT<<<dim3(FDIM / 64, DDIM / 64, NEXP), 256, 0, stream>>>(wgate, wgT, DDIM, FDIM);
    k_convT<<<dim3(FDIM / 64, DDIM / 64, NEXP), 256, 0, stream>>>(wup, wuT, DDIM, FDIM);
    k_convT<<<dim3(DDIM / 64, FDIM / 64, NEXP), 256, 0, stream>>>(wdown, wdT, FDIM, DDIM);
    k_mlp1_gl<<<dim3(FDIM / 128, 16, NEXP), 256, 0, stream>>>(
        xb, wgT, wuT, perm_tok, offs, H);
    k_mlp2_gl<<<dim3(DDIM / 128, 16, NEXP), 256, 0, stream>>>(
        H, wdT, perm_tok, perm_w, offs, out);
  } else if (big) {
    k_mlp1_fb<<<dim3(FDIM / 128, 16, NEXP), 256, 0, stream>>>(
        xb, wgate, wup, perm_tok, offs, 0, -1, H);
    k_mlp2_fb<<<dim3(DDIM / 128, 16, NEXP), 256, 0, stream>>>(
        H, wdown, perm_tok, perm_w, offs, 0, -1, out);
  } else {
    for (int e = 0; e < NEXP; e++) {
      k_mlp1_fb<<<dim3(FDIM / 128, 16, 1), 256, 0, stream>>>(
          xb, wgate, wup, perm_tok, offs, e, 0, H);
      k_mlp2_fb<<<dim3(DDIM / 128, 16, 1), 256, 0, stream>>>(
          H, wdown, perm_tok, perm_w, offs, e, 0, out);
    }
  }
}

// Round 6
// 1404.610 us; speedup vs baseline: 2.2596x; 1.5054x over previous
//
#include <hip/hip_runtime.h>
#include <hip/hip_bf16.h>
#include <cstdint>
#include <cstddef>

#define TNUM 8192
#define DDIM 2048
#define FDIM 4096
#define NEXP 8

typedef __attribute__((ext_vector_type(4))) float f32x4;
typedef __attribute__((ext_vector_type(4))) unsigned u32x4;
typedef __attribute__((ext_vector_type(8))) short s16x8;
typedef __attribute__((ext_vector_type(8))) __bf16 bf16x8v;

__device__ inline f32x4 mfma16(s16x8 a, s16x8 b, f32x4 c) {
  return __builtin_amdgcn_mfma_f32_16x16x32_bf16(
      __builtin_bit_cast(bf16x8v, a), __builtin_bit_cast(bf16x8v, b), c, 0, 0, 0);
}

__device__ inline unsigned short bf16r(float f) {
  union { float f; unsigned u; } x; x.f = f;
  unsigned r = x.u + 0x7fffu + ((x.u >> 16) & 1u);
  return (unsigned short)(r >> 16);
}

__device__ inline unsigned pk2(float a, float b) {
  __hip_bfloat162 h = __float22bfloat162_rn(make_float2(a, b));
  unsigned r;
  __builtin_memcpy(&r, &h, 4);
  return r;
}

// XOR swizzle within 128-byte rows: bijective per row, same fn on write+read
__device__ inline int swz16(int row, int b) {
  return (row << 7) + (b ^ ((row & 7) << 4));
}

typedef const __attribute__((address_space(1))) void* gp_t;
typedef __attribute__((address_space(3))) void* lp_t;
__device__ inline void gl16(const void* g, void* l) {
  __builtin_amdgcn_global_load_lds((gp_t)g, (lp_t)l, 16, 0, 0);
}

#define FENCE asm volatile("" ::: "memory")

// ---------------- router: fp64 logits, top-2 on logits, fp32 softmax values --
__global__ __launch_bounds__(256) void k_router(
    const float* __restrict__ x, const float* __restrict__ gw,
    int* __restrict__ top_idx, float* __restrict__ top_w, int* __restrict__ counts) {
  __shared__ float gwT[NEXP][DDIM];
  const int tid = threadIdx.x;
  for (int i = tid; i < NEXP * DDIM; i += 256) {
    int d = i >> 3, e = i & 7;
    gwT[e][d] = gw[i];
  }
  __syncthreads();
  const int lane = tid & 63;
  const int t = blockIdx.x * 4 + (tid >> 6);
  const float4* xr = (const float4*)(x + (size_t)t * DDIM);
  double acc[NEXP];
#pragma unroll
  for (int e = 0; e < NEXP; e++) acc[e] = 0.0;
  for (int d4 = lane; d4 < DDIM / 4; d4 += 64) {
    float4 xv = xr[d4];
#pragma unroll
    for (int e = 0; e < NEXP; e++) {
      float4 gv = *(const float4*)&gwT[e][d4 * 4];
      acc[e] += (double)xv.x * gv.x + (double)xv.y * gv.y +
                (double)xv.z * gv.z + (double)xv.w * gv.w;
    }
  }
#pragma unroll
  for (int e = 0; e < NEXP; e++) {
    double v = acc[e];
#pragma unroll
    for (int s = 32; s > 0; s >>= 1) v += __shfl_xor(v, s);
    acc[e] = v;
  }
  if (lane == 0) {
    int i0 = 0; double b0 = acc[0];
#pragma unroll
    for (int e = 1; e < NEXP; e++) if (acc[e] > b0) { b0 = acc[e]; i0 = e; }
    int i1 = (i0 == 0) ? 1 : 0; double b1 = acc[i1];
#pragma unroll
    for (int e = 0; e < NEXP; e++) {
      if (e == i0 || e == i1) continue;
      if (acc[e] > b1) { b1 = acc[e]; i1 = e; }
    }
    float lc[NEXP]; float mx = -1e30f;
#pragma unroll
    for (int e = 0; e < NEXP; e++) {
      lc[e] = tanhf((float)(acc[e] * (1.0 / 30.0))) * 30.0f;
      mx = lc[e] > mx ? lc[e] : mx;
    }
    float s = 0.0f;
#pragma unroll
    for (int e = 0; e < NEXP; e++) { lc[e] = expf(lc[e] - mx); s += lc[e]; }
    float inv = 1.0f / s;
    top_idx[t * 2] = i0; top_idx[t * 2 + 1] = i1;
    top_w[t * 2] = lc[i0] * inv; top_w[t * 2 + 1] = lc[i1] * inv;
    atomicAdd(&counts[i0], 1);
    atomicAdd(&counts[i1], 1);
  }
}

__global__ void k_scan(const int* __restrict__ counts, int* __restrict__ offs,
                       int* __restrict__ cursor) {
  if (threadIdx.x == 0) {
    int s = 0;
    for (int e = 0; e < NEXP; e++) { offs[e] = s; cursor[e] = s; s += counts[e]; }
    offs[NEXP] = s;
  }
}

__global__ void k_scatter(const int* __restrict__ top_idx, const float* __restrict__ top_w,
                          int* __restrict__ cursor, int* __restrict__ perm_tok,
                          float* __restrict__ perm_w) {
  int t = blockIdx.x * 256 + threadIdx.x;
#pragma unroll
  for (int k = 0; k < 2; k++) {
    int e = top_idx[t * 2 + k];
    int pos = atomicAdd(&cursor[e], 1);
    perm_tok[pos] = t;
    perm_w[pos] = top_w[t * 2 + k];
  }
}

__global__ void k_cast(const float* __restrict__ x, unsigned short* __restrict__ xb) {
  size_t i = ((size_t)blockIdx.x * 256 + threadIdx.x) * 8;
  f32x4 a = *(const f32x4*)(x + i);
  f32x4 b = *(const f32x4*)(x + i + 4);
  u32x4 v;
  v[0] = pk2(a[0], a[1]); v[1] = pk2(a[2], a[3]);
  v[2] = pk2(b[0], b[1]); v[3] = pk2(b[2], b[3]);
  *(u32x4*)(xb + i) = v;
}

// ---- one-shot: fp32 [E][K][N] -> bf16 [E][n'][K] transpose+convert ----------
// cmap=0: n'=n. cmap=1 (gate): n'=((n>>4)<<5)+(n&15). cmap=2 (up): +16.
__global__ __launch_bounds__(256) void k_convT(
    const float* __restrict__ src, unsigned short* __restrict__ dst,
    int K, int N, int cmap) {
  __shared__ char ct[8192];
  const int e = blockIdx.z;
  const float* src_e = src + (size_t)e * K * N;
  const int nout = cmap ? 2 * N : N;
  unsigned short* dst_e = dst + (size_t)e * nout * K;
  const int k0 = blockIdx.y * 64, n0 = blockIdx.x * 64;
  const int tid = threadIdx.x;
#pragma unroll
  for (int i = 0; i < 4; i++) {
    int idx = tid + i * 256;
    int kr = idx >> 4, f4 = idx & 15;
    f32x4 v = *(const f32x4*)(src_e + (size_t)(k0 + kr) * N + n0 + f4 * 4);
#pragma unroll
    for (int j = 0; j < 4; j++) {
      int n = f4 * 4 + j;
      *(unsigned short*)(ct + n * 128 + ((kr * 2) ^ ((n & 7) << 4))) = bf16r(v[j]);
    }
  }
  __syncthreads();
#pragma unroll
  for (int i = 0; i < 2; i++) {
    int s = tid + i * 256;
    int n = s >> 3, ks = s & 7;
    int gn = n0 + n;
    int cd = cmap ? (((gn >> 4) << 5) + (gn & 15) + (cmap == 2 ? 16 : 0)) : gn;
    s16x8 val = *(const s16x8*)(ct + n * 128 + ((ks * 16) ^ ((n & 7) << 4)));
    *(s16x8*)(dst_e + (size_t)cd * K + k0 + ks * 8) = val;
  }
}

// ======== mlp1: H = gelu(X@Wg) * (X@Wu); Wg/Wu column-interleaved in wguT ====
// 2-phase dbuf pipeline, counted vmcnt, raw barriers.
__global__ __launch_bounds__(256) void k_mlp1(
    const unsigned short* __restrict__ xb, const unsigned short* __restrict__ wguT,
    const int* __restrict__ perm_tok, const int* __restrict__ offs,
    unsigned short* __restrict__ H) {
  __shared__ char lds[65536];  // [2][ A 16KB | B 16KB ]
  const int e = blockIdx.z;
  const int off = offs[e], cnt = offs[e + 1] - off;
  const int nb = blockIdx.x * 128;  // N' panel (N' = 8192)
  const unsigned short* wgu_e = wguT + (size_t)e * 2 * DDIM * FDIM;
  const int tid = threadIdx.x;
  const int lane = tid & 63;
  const int wr = tid >> 7, wc = (tid >> 6) & 1;
  const int l15 = lane & 15, lk = lane >> 4;
  const int wbase = (tid >> 6) * 1024;

#pragma unroll 1
  for (int mt = blockIdx.y; mt * 128 < cnt; mt += 16) {
    const unsigned short* asrc[4];
    const unsigned short* bsrc[4];
#pragma unroll
    for (int i = 0; i < 4; i++) {
      int seg = tid + i * 256;
      int m = seg >> 3, kp = (seg & 7) ^ (m & 7);
      int gm = mt * 128 + m;
      if (gm >= cnt) gm = cnt - 1;
      asrc[i] = xb + (size_t)perm_tok[off + gm] * DDIM + kp * 8;
      bsrc[i] = wgu_e + (size_t)(nb + m) * DDIM + kp * 8;
    }
    f32x4 acc[4][4];
#pragma unroll
    for (int mi = 0; mi < 4; mi++)
#pragma unroll
      for (int ni = 0; ni < 4; ni++) acc[mi][ni] = f32x4{0.f, 0.f, 0.f, 0.f};

#define STAGE1(buf, koff)                                        \
    {                                                            \
      char* As_ = lds + (buf) * 32768;                           \
      char* Bs_ = As_ + 16384;                                   \
      _Pragma("unroll") for (int i = 0; i < 4; i++) {            \
        gl16(asrc[i] + (koff), As_ + i * 4096 + wbase);          \
        gl16(bsrc[i] + (koff), Bs_ + i * 4096 + wbase);          \
      }                                                          \
    }

    STAGE1(0, 0);
    int cur = 0;
#pragma unroll 1
    for (int t = 0; t < DDIM / 64; t++) {
      if (t + 1 < DDIM / 64) {
        STAGE1(cur ^ 1, (t + 1) * 64);
        asm volatile("s_waitcnt vmcnt(8)" ::: "memory");
      } else {
        asm volatile("s_waitcnt vmcnt(0)" ::: "memory");
      }
      FENCE;
      __builtin_amdgcn_s_barrier();
      FENCE;
      {
        char* As_ = lds + cur * 32768;
        char* Bs_ = As_ + 16384;
#pragma unroll
        for (int ks = 0; ks < 2; ks++) {
          s16x8 a[4];
#pragma unroll
          for (int mi = 0; mi < 4; mi++)
            a[mi] = *(const s16x8*)(As_ + swz16(wr * 64 + mi * 16 + l15, ks * 64 + lk * 16));
#pragma unroll
          for (int ni = 0; ni < 4; ni++) {
            s16x8 b = *(const s16x8*)(Bs_ + swz16(wc * 64 + ni * 16 + l15, ks * 64 + lk * 16));
#pragma unroll
            for (int mi = 0; mi < 4; mi++) acc[mi][ni] = mfma16(a[mi], b, acc[mi][ni]);
          }
        }
      }
      FENCE;
      __builtin_amdgcn_s_barrier();
      FENCE;
      cur ^= 1;
    }
#undef STAGE1

    // epilogue: acc[.][even]=gate, acc[.][odd]=up for the same 16 H-cols
#pragma unroll
    for (int mi = 0; mi < 4; mi++) {
      int rb = wr * 64 + mi * 16 + lk * 4;
#pragma unroll
      for (int j = 0; j < 4; j++) {
        int gm = mt * 128 + rb + j;
        if (gm < cnt) {
          unsigned short* hrow = H + (size_t)(off + gm) * FDIM;
#pragma unroll
          for (int ni = 0; ni < 4; ni += 2) {
            int jj = (nb >> 4) + wc * 4 + ni;
            int hc = ((jj >> 1) << 4) + l15;
            float g = acc[mi][ni][j];
            float u = acc[mi][ni + 1][j];
            float x3 = g * g * g;
            float gl = 0.5f * g * (1.0f + tanhf(0.7978845608f * (g + 0.044715f * x3)));
            hrow[hc] = bf16r(gl * u);
          }
        }
      }
    }
  }
}

// ======== mlp2: out += w * (He @ Wd), 2-phase dbuf pipeline ==================
__global__ __launch_bounds__(256) void k_mlp2(
    const unsigned short* __restrict__ H, const unsigned short* __restrict__ wdT,
    const int* __restrict__ perm_tok, const float* __restrict__ perm_w,
    const int* __restrict__ offs, float* __restrict__ out) {
  __shared__ char lds[65536];
  const int e = blockIdx.z;
  const int off = offs[e], cnt = offs[e + 1] - off;
  const int nb = blockIdx.x * 128;
  const unsigned short* wd_e = wdT + (size_t)e * FDIM * DDIM;  // [n=D][k=F]
  const int tid = threadIdx.x;
  const int lane = tid & 63;
  const int wr = tid >> 7, wc = (tid >> 6) & 1;
  const int l15 = lane & 15, lk = lane >> 4;
  const int wbase = (tid >> 6) * 1024;

#pragma unroll 1
  for (int mt = blockIdx.y; mt * 128 < cnt; mt += 16) {
    const unsigned short* asrc[4];
    const unsigned short* bsrc[4];
#pragma unroll
    for (int i = 0; i < 4; i++) {
      int seg = tid + i * 256;
      int m = seg >> 3, kp = (seg & 7) ^ (m & 7);
      int gm = mt * 128 + m;
      if (gm >= cnt) gm = cnt - 1;
      asrc[i] = H + (size_t)(off + gm) * FDIM + kp * 8;
      bsrc[i] = wd_e + (size_t)(nb + m) * FDIM + kp * 8;
    }
    f32x4 acc[4][4];
#pragma unroll
    for (int mi = 0; mi < 4; mi++)
#pragma unroll
      for (int ni = 0; ni < 4; ni++) acc[mi][ni] = f32x4{0.f, 0.f, 0.f, 0.f};

#define STAGE2(buf, koff)                                        \
    {                                                            \
      char* As_ = lds + (buf) * 32768;                           \
      char* Bs_ = As_ + 16384;                                   \
      _Pragma("unroll") for (int i = 0; i < 4; i++) {            \
        gl16(asrc[i] + (koff), As_ + i * 4096 + wbase);          \
        gl16(bsrc[i] + (koff), Bs_ + i * 4096 + wbase);          \
      }                                                          \
    }

    STAGE2(0, 0);
    int cur = 0;
#pragma unroll 1
    for (int t = 0; t < FDIM / 64; t++) {
      if (t + 1 < FDIM / 64) {
        STAGE2(cur ^ 1, (t + 1) * 64);
        asm volatile("s_waitcnt vmcnt(8)" ::: "memory");
      } else {
        asm volatile("s_waitcnt vmcnt(0)" ::: "memory");
      }
      FENCE;
      __builtin_amdgcn_s_barrier();
      FENCE;
      {
        char* As_ = lds + cur * 32768;
        char* Bs_ = As_ + 16384;
#pragma unroll
        for (int ks = 0; ks < 2; ks++) {
          s16x8 a[4];
#pragma unroll
          for (int mi = 0; mi < 4; mi++)
            a[mi] = *(const s16x8*)(As_ + swz16(wr * 64 + mi * 16 + l15, ks * 64 + lk * 16));
#pragma unroll
          for (int ni = 0; ni < 4; ni++) {
            s16x8 b = *(const s16x8*)(Bs_ + swz16(wc * 64 + ni * 16 + l15, ks * 64 + lk * 16));
#pragma unroll
            for (int mi = 0; mi < 4; mi++) acc[mi][ni] = mfma16(a[mi], b, acc[mi][ni]);
          }
        }
      }
      FENCE;
      __builtin_amdgcn_s_barrier();
      FENCE;
      cur ^= 1;
    }
#undef STAGE2

#pragma unroll
    for (int mi = 0; mi < 4; mi++) {
      int rb = wr * 64 + mi * 16 + lk * 4;
#pragma unroll
      for (int j = 0; j < 4; j++) {
        int gm = mt * 128 + rb + j;
        if (gm < cnt) {
          int tok = perm_tok[off + gm];
          float w = perm_w[off + gm];
          float* orow = out + (size_t)tok * DDIM + nb + wc * 64 + l15;
#pragma unroll
          for (int ni = 0; ni < 4; ni++) atomicAdd(&orow[ni * 16], w * acc[mi][ni][j]);
        }
      }
    }
  }
}

extern "C" void kernel_launch(void* const* d_in, const int* in_sizes, int n_in,
                              void* d_out, int out_size, void* d_ws, size_t ws_size,
                              hipStream_t stream) {
  const float* x = (const float*)d_in[0];
  const float* gw = (const float*)d_in[1];
  const float* wgate = (const float*)d_in[2];
  const float* wup = (const float*)d_in[3];
  const float* wdown = (const float*)d_in[4];
  float* out = (float*)d_out;

  const size_t XB_B = 33554432;                  // xb bf16 [8192][2048]
  const size_t H_B = 134217728;                  // H bf16 [16384][4096]
  const size_t WGU_B = 268435456;                // wguT bf16 [E][8192][2048]
  const size_t WD_B = 134217728;                 // wdT bf16 [E][2048][4096]

  char* ws = (char*)d_ws;
  unsigned short* xb = (unsigned short*)ws;
  unsigned short* H = (unsigned short*)(ws + XB_B);
  unsigned short* wguT = (unsigned short*)(ws + XB_B + H_B);
  unsigned short* wdT = (unsigned short*)(ws + XB_B + H_B + WGU_B);
  char* meta = ws + XB_B + H_B + WGU_B + WD_B;
  int* counts = (int*)(meta);
  int* offs = (int*)(meta + 64);
  int* cursor = (int*)(meta + 128);
  int* top_idx = (int*)(meta + 256);
  float* top_w = (float*)(meta + 256 + 65536);
  int* perm_tok = (int*)(meta + 256 + 131072);
  float* perm_w = (float*)(meta + 256 + 196608);

  (void)hipMemsetAsync(counts, 0, 64, stream);
  (void)hipMemsetAsync(d_out, 0, (size_t)TNUM * DDIM * 4, stream);
  k_router<<<TNUM / 4, 256, 0, stream>>>(x, gw, top_idx, top_w, counts);
  k_scan<<<1, 64, 0, stream>>>(counts, offs, cursor);
  k_scatter<<<TNUM / 256, 256, 0, stream>>>(top_idx, top_w, cursor, perm_tok, perm_w);
  k_cast<<<(TNUM * DDIM / 8) / 256, 256, 0, stream>>>(x, xb);
  k_convT<<<dim3(FDIM / 64, DDIM / 64, NEXP), 256, 0, stream>>>(wgate, wguT, DDIM, FDIM, 1);
  k_convT<<<dim3(FDIM / 64, DDIM / 64, NEXP), 256, 0, stream>>>(wup, wguT, DDIM, FDIM, 2);
  k_convT<<<dim3(DDIM / 64, FDIM / 64, NEXP), 256, 0, stream>>>(wdown, wdT, FDIM, DDIM, 0);
  k_mlp1<<<dim3(2 * FDIM / 128, 16, NEXP), 256, 0, stream>>>(xb, wguT, perm_tok, offs, H);
  k_mlp2<<<dim3(DDIM / 128, 16, NEXP), 256, 0, stream>>>(H, wdT, perm_tok, perm_w, offs, out);
}